// Round 1
// baseline (1355.829 us; speedup 1.0000x reference)
//
#include <hip/hip_runtime.h>

// ---------------- constants ----------------
#define KTOP 50
#define TT 50
#define VV 3000
#define LL 300
#define THH 800
#define EHH 200
#define DD 256
#define LOG_DELTA (-5.2983173665480363f)
#define DEN_DELTA (0.005f + 1e-6f)

typedef _Float16 half2_t __attribute__((ext_vector_type(2)));
union H8 { float4 f4; half2_t h2[4]; };

__device__ __forceinline__ float fdot2f(half2_t a, half2_t b, float c) {
#if __has_builtin(__builtin_amdgcn_fdot2)
    return __builtin_amdgcn_fdot2(a, b, c, false);
#else
    return c + (float)a.x * (float)b.x + (float)a.y * (float)b.y;
#endif
}
__device__ __forceinline__ float sigm(float x) { return 1.0f / (1.0f + __expf(-x)); }
__device__ __forceinline__ float tanh_fast(float x) {
    float e = __expf(2.0f * x);
    return 1.0f - 2.0f / (e + 1.0f);
}

// ---------------- ws layout (float offsets) ----------------
#define WS_X      0         // 50*200
#define WS_XW0    10000     // 50*800
#define WS_XW1    50000     // 50*800
#define WS_HS0    90000     // 50*200
#define WS_HS1    100000    // 50*200
#define WS_ETAS   110000    // 50*50
#define WS_H1     112500    // 256*800
#define WS_H2     317300    // 256*800
#define WS_MUL    522100    // 256*100
#define WS_THETA  547700    // 256*50
#define WS_RHOH   560512    // 3000*304 halves (456000 float slots)

// ---------------- zero ws accumulators + out ----------------
__global__ void k_zero(float* __restrict__ wsh, int n, float* __restrict__ out) {
    int i = blockIdx.x * 256 + threadIdx.x;
    if (i < n) wsh[i] = 0.f;
    if (blockIdx.x == 0 && threadIdx.x < 4) out[threadIdx.x] = 0.f;
}

// ---------------- kl_alpha ----------------
__global__ void k_klalpha(const float* __restrict__ qm, const float* __restrict__ ql,
                          float* __restrict__ out) {
    __shared__ float sred[256];
    float s = 0.f;
    const int NTOT = KTOP * TT * LL;
    for (int idx = blockIdx.x * 256 + threadIdx.x; idx < NTOT; idx += gridDim.x * 256) {
        int r = idx % (TT * LL);
        float m = qm[idx], l = ql[idx];
        float term;
        if (r < LL) {
            term = 0.5f * ((__expf(l) + m * m) * (1.0f / (1.0f + 1e-6f)) - 1.0f - l);
        } else {
            float pm = qm[idx - LL];
            float dm = m - pm;
            term = 0.5f * ((__expf(l) + dm * dm) * (1.0f / DEN_DELTA) - 1.0f + LOG_DELTA - l);
        }
        s += term;
    }
    sred[threadIdx.x] = s;
    __syncthreads();
    for (int off = 128; off > 0; off >>= 1) {
        if (threadIdx.x < off) sred[threadIdx.x] += sred[threadIdx.x + off];
        __syncthreads();
    }
    if (threadIdx.x == 0) atomicAdd(out + 1, sred[0]);
}

// ---------------- rho -> f16 (rows padded to 304) ----------------
__global__ void k_rho16(const float* __restrict__ rho, _Float16* __restrict__ rho_h) {
    int idx = blockIdx.x * 256 + threadIdx.x;
    if (idx >= VV * 304) return;
    int v = idx / 304, l = idx - v * 304;
    rho_h[idx] = (_Float16)((l < LL) ? rho[v * LL + l] : 0.f);
}

// ---------------- x = rnn_inp @ W_em + b_em ----------------
__global__ __launch_bounds__(256) void k_embed(const float* __restrict__ rnn,
                                               const float* __restrict__ W_em,
                                               const float* __restrict__ b_em,
                                               float* __restrict__ x) {
    int t = blockIdx.x, e = threadIdx.x;
    if (e >= EHH) return;
    float a0 = 0.f, a1 = 0.f, a2 = 0.f, a3 = 0.f;
    for (int v = 0; v < VV; v += 4) {
        float r0 = rnn[t * VV + v], r1 = rnn[t * VV + v + 1];
        float r2 = rnn[t * VV + v + 2], r3 = rnn[t * VV + v + 3];
        a0 += r0 * W_em[(size_t)(v) * EHH + e];
        a1 += r1 * W_em[(size_t)(v + 1) * EHH + e];
        a2 += r2 * W_em[(size_t)(v + 2) * EHH + e];
        a3 += r3 * W_em[(size_t)(v + 3) * EHH + e];
    }
    x[t * EHH + e] = (a0 + a1) + (a2 + a3) + b_em[e];
}

// ---------------- xW = src @ Wih + bias  (per-t block) ----------------
__global__ __launch_bounds__(256) void k_xw(const float* __restrict__ src,
                                            const float* __restrict__ Wih,
                                            const float* __restrict__ bias,
                                            float* __restrict__ dst) {
    int t = blockIdx.x, tid = threadIdx.x;
    __shared__ float xs[EHH];
    if (tid < EHH) xs[tid] = src[t * EHH + tid];
    __syncthreads();
    for (int j = tid; j < 4 * EHH; j += 256) {
        float a0 = 0.f, a1 = 0.f;
        #pragma unroll 4
        for (int e = 0; e < EHH; e += 2) {
            a0 += xs[e] * Wih[(size_t)e * 800 + j];
            a1 += xs[e + 1] * Wih[(size_t)(e + 1) * 800 + j];
        }
        dst[t * 800 + j] = a0 + a1 + bias[j];
    }
}

// ---------------- LSTM layer: persistent single block, Whh in f16 VGPRs ----------------
__global__ __launch_bounds__(448) void k_lstm(const float* __restrict__ xW,
                                              const float* __restrict__ Whh,
                                              float* __restrict__ hs) {
    const int tid = threadIdx.x;
    __shared__ _Float16 hbuf[EHH];
    __shared__ float gbuf[800];
    half2_t w0[100], w1[100];
    const int c0 = tid, c1 = tid + 400;
    if (tid < 400) {
        #pragma unroll
        for (int e2 = 0; e2 < 100; ++e2) {
            half2_t a, b;
            a.x = (_Float16)Whh[(size_t)(2 * e2) * 800 + c0];
            a.y = (_Float16)Whh[(size_t)(2 * e2 + 1) * 800 + c0];
            b.x = (_Float16)Whh[(size_t)(2 * e2) * 800 + c1];
            b.y = (_Float16)Whh[(size_t)(2 * e2 + 1) * 800 + c1];
            w0[e2] = a; w1[e2] = b;
        }
    }
    float creg = 0.f;
    if (tid < EHH) hbuf[tid] = (_Float16)0.f;
    __syncthreads();
    for (int t = 0; t < TT; ++t) {
        if (tid < 400) {
            float a0 = xW[t * 800 + c0], a1 = xW[t * 800 + c1];
            const half2_t* hp = (const half2_t*)hbuf;
            #pragma unroll
            for (int e2 = 0; e2 < 100; ++e2) {
                half2_t h2 = hp[e2];
                a0 = fdot2f(w0[e2], h2, a0);
                a1 = fdot2f(w1[e2], h2, a1);
            }
            gbuf[c0] = a0; gbuf[c1] = a1;
        }
        __syncthreads();
        if (tid < EHH) {
            float gi = gbuf[tid], gf = gbuf[tid + 200];
            float gg = gbuf[tid + 400], go = gbuf[tid + 600];
            float c2 = sigm(gf) * creg + sigm(gi) * tanh_fast(gg);
            creg = c2;
            float h2v = sigm(go) * tanh_fast(c2);
            hs[t * EHH + tid] = h2v;
            hbuf[tid] = (_Float16)h2v;
        }
        __syncthreads();
    }
}

// ---------------- eta scan (estep): single block, weights f16 in LDS ----------------
__global__ __launch_bounds__(256) void k_estep(const float* __restrict__ hs1,
                                               const float* __restrict__ Wmu,
                                               const float* __restrict__ Wls,
                                               const float* __restrict__ bmu,
                                               const float* __restrict__ bls,
                                               float* __restrict__ etas,
                                               float* __restrict__ out) {
    const int tid = threadIdx.x;
    __shared__ _Float16 Wt[100 * 252];
    __shared__ _Float16 cath[252];
    __shared__ float red[200];
    __shared__ float mubuf[50], lsbuf[50], etabuf[50], klterm[50];
    __shared__ float klacc;
    for (int idx = tid; idx < 100 * 252; idx += 256) {
        int j = idx / 252, e = idx - j * 252;
        float v = 0.f;
        if (e < 250) v = (j < 50) ? Wmu[e * 50 + j] : Wls[e * 50 + (j - 50)];
        Wt[idx] = (_Float16)v;
    }
    if (tid < 50) etabuf[tid] = 0.f;
    if (tid == 0) klacc = 0.f;
    __syncthreads();
    for (int t = 0; t < TT; ++t) {
        if (tid < 200) cath[tid] = (_Float16)hs1[t * EHH + tid];
        else if (tid < 250) cath[tid] = (_Float16)etabuf[tid - 200];
        else if (tid < 252) cath[tid] = (_Float16)0.f;
        __syncthreads();
        if (tid < 200) {
            int j = tid % 100, p = tid / 100;
            int b = p * 63;
            const half2_t* wr = (const half2_t*)&Wt[j * 252];
            const half2_t* cp = (const half2_t*)cath;
            float a0 = 0.f, a1 = 0.f;
            for (int e2 = b; e2 < b + 63; e2 += 2) a0 = fdot2f(wr[e2], cp[e2], a0);
            for (int e2 = b + 1; e2 < b + 63; e2 += 2) a1 = fdot2f(wr[e2], cp[e2], a1);
            red[tid] = a0 + a1;
        }
        __syncthreads();
        if (tid < 100) {
            float s = red[tid] + red[100 + tid] + ((tid < 50) ? bmu[tid] : bls[tid - 50]);
            if (tid < 50) mubuf[tid] = s; else lsbuf[tid - 50] = s;
        }
        __syncthreads();
        if (tid < 50) {
            float mu = mubuf[tid], ls = lsbuf[tid], ep = etabuf[tid];
            float den = (t == 0) ? (1.0f + 1e-6f) : DEN_DELTA;
            float pls = (t == 0) ? 0.f : LOG_DELTA;
            float dm = mu - ep;
            klterm[tid] = 0.5f * ((__expf(ls) + dm * dm) / den - 1.0f + pls - ls);
            etas[t * 50 + tid] = mu;
        }
        __syncthreads();
        if (tid < 50) etabuf[tid] = mubuf[tid];
        if (tid == 0) {
            float s = 0.f;
            for (int k2 = 0; k2 < 50; ++k2) s += klterm[k2];
            klacc += s;
        }
        __syncthreads();
    }
    if (tid == 0) atomicAdd(out + 2, klacc);
}

// ---------------- fp32 GEMM, 32x32 tile, K-split via blockIdx.z, atomicAdd partials ----------------
// AMODE 0: A dense (ld=Kd).  AMODE 1: A = [bows | etas[times]] (Kd=3050)
// BMODE 0: B dense (ld=N).   BMODE 1: B = [W_mu_th | W_ls_th]   (N=100)
template <int AMODE, int BMODE>
__global__ __launch_bounds__(64) void k_gemm(const float* __restrict__ A,
                                             const float* __restrict__ B,
                                             float* __restrict__ C, int N, int Kd, int KC,
                                             const float* __restrict__ bows,
                                             const float* __restrict__ etas,
                                             const int* __restrict__ times,
                                             const float* __restrict__ B2) {
    const int tid = threadIdx.x;
    const int bx = blockIdx.x, by = blockIdx.y, bz = blockIdx.z;
    const int kbeg = bz * KC;
    const int kend = min(Kd, kbeg + KC);
    __shared__ __align__(16) float As[16][32];
    __shared__ __align__(16) float Bs[16][32];
    float acc[4][4] = {};
    const int tx = tid & 7, ty = tid >> 3;
    const int am = tid >> 1;
    const int akb = (tid & 1) * 8;
    const int gm = by * 32 + am;
    int tmi = 0;
    if (AMODE == 1) tmi = times[gm];
    const int bkk = tid >> 2;
    const int bnb = (tid & 3) * 8;
    for (int k0 = kbeg; k0 < kend; k0 += 16) {
        #pragma unroll
        for (int u = 0; u < 8; ++u) {
            int k = k0 + akb + u;
            float v = 0.f;
            if (k < kend) {
                if (AMODE == 0) v = A[(size_t)gm * Kd + k];
                else v = (k < 3000) ? bows[(size_t)gm * 3000 + k]
                                    : etas[tmi * 50 + (k - 3000)];
            }
            As[akb + u][am] = v;
        }
        {
            int k = k0 + bkk;
            #pragma unroll
            for (int u = 0; u < 8; ++u) {
                int n = bx * 32 + bnb + u;
                float v = 0.f;
                if (k < kend && n < N) {
                    if (BMODE == 0) v = B[(size_t)k * N + n];
                    else v = (n < 50) ? B[k * 50 + n] : B2[k * 50 + (n - 50)];
                }
                Bs[bkk][bnb + u] = v;
            }
        }
        __syncthreads();
        #pragma unroll
        for (int kk = 0; kk < 16; ++kk) {
            float4 a4 = *(const float4*)&As[kk][ty * 4];
            float4 b4 = *(const float4*)&Bs[kk][tx * 4];
            float av[4] = {a4.x, a4.y, a4.z, a4.w};
            float bv[4] = {b4.x, b4.y, b4.z, b4.w};
            #pragma unroll
            for (int i = 0; i < 4; ++i)
                #pragma unroll
                for (int j = 0; j < 4; ++j) acc[i][j] += av[i] * bv[j];
        }
        __syncthreads();
    }
    #pragma unroll
    for (int i = 0; i < 4; ++i) {
        int m = by * 32 + ty * 4 + i;
        #pragma unroll
        for (int j = 0; j < 4; ++j) {
            int n = bx * 32 + tx * 4 + j;
            if (n < N) atomicAdd(&C[(size_t)m * N + n], acc[i][j]);
        }
    }
}

// ---------------- bias + relu epilogue ----------------
__global__ void k_bias_relu(float* __restrict__ X, const float* __restrict__ b, int n, int ld) {
    int i = blockIdx.x * 256 + threadIdx.x;
    if (i < n) {
        float v = X[i] + b[i % ld];
        X[i] = v > 0.f ? v : 0.f;
    }
}

// ---------------- softmax(theta) + kl_theta ----------------
__global__ __launch_bounds__(64) void k_softkl(const float* __restrict__ mul,
                                               const float* __restrict__ bmu,
                                               const float* __restrict__ bls,
                                               const float* __restrict__ etas,
                                               const int* __restrict__ times,
                                               float* __restrict__ theta,
                                               float* __restrict__ out) {
    int d = blockIdx.x, k = threadIdx.x;
    int td = times[d];
    float muv = -1e30f, lsv = 0.f, etav = 0.f;
    if (k < 50) {
        muv = mul[d * 100 + k] + bmu[k];
        lsv = mul[d * 100 + 50 + k] + bls[k];
        etav = etas[td * 50 + k];
    }
    float mx = muv;
    #pragma unroll
    for (int m = 1; m < 64; m <<= 1) mx = fmaxf(mx, __shfl_xor(mx, m, 64));
    float e = (k < 50) ? __expf(muv - mx) : 0.f;
    float ssum = e;
    #pragma unroll
    for (int m = 1; m < 64; m <<= 1) ssum += __shfl_xor(ssum, m, 64);
    if (k < 50) theta[d * 50 + k] = e / ssum;
    float kt = 0.f;
    if (k < 50) {
        float dm = muv - etav;
        kt = 0.5f * ((__expf(lsv) + dm * dm) * (1.0f / (1.0f + 1e-6f)) - 1.0f - lsv);
    }
    #pragma unroll
    for (int m = 1; m < 64; m <<= 1) kt += __shfl_xor(kt, m, 64);
    if (k == 0) atomicAdd(out + 3, kt);
}

// ---------------- big NLL kernel: one block per document ----------------
__global__ __launch_bounds__(512) void k_bignll(const float* __restrict__ bows,
                                                const int* __restrict__ times,
                                                const int* __restrict__ sources,
                                                const float* __restrict__ mu_a,
                                                const float* __restrict__ lam,
                                                const _Float16* __restrict__ rho_h,
                                                const float* __restrict__ theta,
                                                float* __restrict__ out) {
    const int tid = threadIdx.x, d = blockIdx.x;
    const int td = times[d], sd = sources[d];
    __shared__ __align__(16) _Float16 wl[7 * 304];
    __shared__ __align__(4) _Float16 El[7 * 3000];
    __shared__ float lik[3000];
    __shared__ float redZ[8 * 8];
    __shared__ float coefS[8];
    __shared__ float nred[8];
    const int lane = tid & 63, wid = tid >> 6;
    for (int v = tid; v < VV; v += 512) lik[v] = 0.f;
    for (int g = 0; g < 8; ++g) {
        __syncthreads();
        const int k0 = g * 7;
        for (int idx = tid; idx < 7 * 304; idx += 512) {
            int kk = idx / 304, l = idx - kk * 304;
            int kglob = k0 + kk;
            float v = 0.f;
            if (kglob < KTOP && l < LL)
                v = mu_a[(size_t)kglob * (TT * LL) + td * LL + l] * lam[sd * LL + l];
            wl[idx] = (_Float16)v;
        }
        __syncthreads();
        float Zp[7] = {0.f, 0.f, 0.f, 0.f, 0.f, 0.f, 0.f};
        for (int vb = 0; vb < 3; ++vb) {
            int v0 = vb * 1024 + tid * 2;
            if (v0 < VV) {
                float acc[7][2] = {};
                const float4* ra4 = (const float4*)(rho_h + (size_t)v0 * 304);
                const float4* rb4 = (const float4*)(rho_h + (size_t)(v0 + 1) * 304);
                #pragma unroll 2
                for (int lq = 0; lq < 38; ++lq) {
                    H8 ra, rb;
                    ra.f4 = ra4[lq];
                    rb.f4 = rb4[lq];
                    #pragma unroll
                    for (int kk = 0; kk < 7; ++kk) {
                        H8 wv;
                        wv.f4 = ((const float4*)&wl[kk * 304])[lq];
                        #pragma unroll
                        for (int q = 0; q < 4; ++q) {
                            acc[kk][0] = fdot2f(wv.h2[q], ra.h2[q], acc[kk][0]);
                            acc[kk][1] = fdot2f(wv.h2[q], rb.h2[q], acc[kk][1]);
                        }
                    }
                }
                #pragma unroll
                for (int kk = 0; kk < 7; ++kk) {
                    float e0 = __expf(acc[kk][0]);
                    float e1 = __expf(acc[kk][1]);
                    half2_t ev;
                    ev.x = (_Float16)e0;
                    ev.y = (_Float16)e1;
                    *(half2_t*)&El[kk * 3000 + v0] = ev;
                    Zp[kk] += e0 + e1;
                }
            }
        }
        #pragma unroll
        for (int kk = 0; kk < 7; ++kk) {
            float z = Zp[kk];
            #pragma unroll
            for (int m = 1; m < 64; m <<= 1) z += __shfl_xor(z, m, 64);
            if (lane == 0) redZ[wid * 8 + kk] = z;
        }
        __syncthreads();
        if (tid < 7) {
            float z = 0.f;
            #pragma unroll
            for (int w = 0; w < 8; ++w) z += redZ[w * 8 + tid];
            int kglob = k0 + tid;
            coefS[tid] = (kglob < KTOP) ? theta[d * 50 + kglob] / z : 0.f;
        }
        __syncthreads();
        for (int v = tid; v < VV; v += 512) {
            float s2 = lik[v];
            #pragma unroll
            for (int kk = 0; kk < 7; ++kk) s2 += coefS[kk] * (float)El[kk * 3000 + v];
            lik[v] = s2;
        }
    }
    __syncthreads();
    float nl = 0.f;
    for (int v = tid; v < VV; v += 512) nl += logf(lik[v] + 1e-6f) * bows[(size_t)d * VV + v];
    #pragma unroll
    for (int m = 1; m < 64; m <<= 1) nl += __shfl_xor(nl, m, 64);
    if (lane == 0) nred[wid] = nl;
    __syncthreads();
    if (tid == 0) {
        float s2 = 0.f;
        #pragma unroll
        for (int w = 0; w < 8; ++w) s2 += nred[w];
        atomicAdd(out + 0, -s2);
    }
}

// ---------------- host launcher ----------------
extern "C" void kernel_launch(void* const* d_in, const int* in_sizes, int n_in,
                              void* d_out, int out_size, void* d_ws, size_t ws_size,
                              hipStream_t stream) {
    const float* bows    = (const float*)d_in[0];
    const float* rnn     = (const float*)d_in[1];
    const int*   times   = (const int*)d_in[2];
    const int*   sources = (const int*)d_in[3];
    const float* rho     = (const float*)d_in[4];
    const float* lam     = (const float*)d_in[5];
    const float* mu_a    = (const float*)d_in[6];
    const float* ls_a    = (const float*)d_in[7];
    const float* W_t1    = (const float*)d_in[8];
    const float* b_t1    = (const float*)d_in[9];
    const float* W_t2    = (const float*)d_in[10];
    const float* b_t2    = (const float*)d_in[11];
    const float* W_mu_th = (const float*)d_in[12];
    const float* b_mu_th = (const float*)d_in[13];
    const float* W_ls_th = (const float*)d_in[14];
    const float* b_ls_th = (const float*)d_in[15];
    const float* W_em    = (const float*)d_in[16];
    const float* b_em    = (const float*)d_in[17];
    const float* Wih0    = (const float*)d_in[18];
    const float* Whh0    = (const float*)d_in[19];
    const float* bl0     = (const float*)d_in[20];
    const float* Wih1    = (const float*)d_in[21];
    const float* Whh1    = (const float*)d_in[22];
    const float* bl1     = (const float*)d_in[23];
    const float* W_mu_e  = (const float*)d_in[24];
    const float* b_mu_e  = (const float*)d_in[25];
    const float* W_ls_e  = (const float*)d_in[26];
    const float* b_ls_e  = (const float*)d_in[27];

    float* ws  = (float*)d_ws;
    float* out = (float*)d_out;
    float* x     = ws + WS_X;
    float* xw0   = ws + WS_XW0;
    float* xw1   = ws + WS_XW1;
    float* hs0   = ws + WS_HS0;
    float* hs1   = ws + WS_HS1;
    float* etas  = ws + WS_ETAS;
    float* h1    = ws + WS_H1;
    float* h2    = ws + WS_H2;
    float* mul   = ws + WS_MUL;
    float* theta = ws + WS_THETA;
    _Float16* rho_h = (_Float16*)(ws + WS_RHOH);

    // zero atomic-accumulated regions (h1,h2,mul are contiguous) + out
    k_zero<<<1700, 256, 0, stream>>>(h1, 435200, out);
    // independent reductions / conversions
    k_klalpha<<<512, 256, 0, stream>>>(mu_a, ls_a, out);
    k_rho16<<<(VV * 304 + 255) / 256, 256, 0, stream>>>(rho, rho_h);
    // sequential chain
    k_embed<<<50, 256, 0, stream>>>(rnn, W_em, b_em, x);
    k_xw<<<50, 256, 0, stream>>>(x, Wih0, bl0, xw0);
    k_lstm<<<1, 448, 0, stream>>>(xw0, Whh0, hs0);
    k_xw<<<50, 256, 0, stream>>>(hs0, Wih1, bl1, xw1);
    k_lstm<<<1, 448, 0, stream>>>(xw1, Whh1, hs1);
    k_estep<<<1, 256, 0, stream>>>(hs1, W_mu_e, W_ls_e, b_mu_e, b_ls_e, etas, out);
    // theta MLP
    k_gemm<1, 0><<<dim3(25, 8, 4), 64, 0, stream>>>(nullptr, W_t1, h1, 800, 3050, 768,
                                                    bows, etas, times, nullptr);
    k_bias_relu<<<800, 256, 0, stream>>>(h1, b_t1, 204800, 800);
    k_gemm<0, 0><<<dim3(25, 8, 4), 64, 0, stream>>>(h1, W_t2, h2, 800, 800, 200,
                                                    nullptr, nullptr, times, nullptr);
    k_bias_relu<<<800, 256, 0, stream>>>(h2, b_t2, 204800, 800);
    k_gemm<0, 1><<<dim3(4, 8, 8), 64, 0, stream>>>(h2, W_mu_th, mul, 100, 800, 100,
                                                   nullptr, nullptr, times, W_ls_th);
    k_softkl<<<256, 64, 0, stream>>>(mul, b_mu_th, b_ls_th, etas, times, theta, out);
    // big softmax-einsum NLL
    k_bignll<<<256, 512, 0, stream>>>(bows, times, sources, mu_a, lam, rho_h, theta, out);
}